// Round 2
// baseline (7104.320 us; speedup 1.0000x reference)
//
#include <hip/hip_runtime.h>
#include <math.h>

#define NFFT   1024
#define NH     512      // NFFT/2 (complex FFT size)
#define NQ     256      // NH/2 (one radix-2 butterfly per thread)
#define HOP    64
#define NMELS  80
#define NFR    512      // frames
#define NBINS  513
#define NITER  300
#define SIGLEN 33728
#define NT     256      // block size

// ---- workspace layout (float offsets) ----
#define TBL_WIN  0          // win[1024]
#define TBL_TWR  1024       // twr[256]
#define TBL_TWI  1280       // twi[256]
#define TBL_W1R  1536       // w1r[513]
#define TBL_W1I  2056       // w1i[513]
#define OFF_MAG  4096                     // mag[512*513]
#define OFF_IWS  (OFF_MAG + NBINS * NFR)  // 266752: iws[33728]
#define OFF_F0   300480                   // F0[512*1024]
#define OFF_F1   (OFF_F0 + NFR * NFFT)    // F1[512*1024]
// total = 1,348,544 floats ~= 5.4 MB

struct SMem {
    float Ar[NH], Ai[NH];         // FFT ping
    float Br[NH], Bi[NH];         // FFT pong
    float Xr[NBINS], Xi[NBINS];   // spectrum column
    float mag[NBINS];             // target magnitude column
    float win[NFFT];
    float twr[NQ], twi[NQ];       // e^{-2pi i j/512}
    float w1r[NBINS], w1i[NBINS]; // e^{+2pi i k/1024}
    float xb[NFFT];               // time-domain frame scratch
};

// Stockham radix-2 complex FFT, N=512, 256 threads, natural order in/out.
__device__ __forceinline__ void fft512(float*& sr, float*& si, float*& dr, float*& di,
                                       const float* twr, const float* twi,
                                       int tid, bool inverse) {
#pragma unroll
    for (int s = 0; s < 9; ++s) {
        const int p = 1 << s;
        __syncthreads();
        int k  = tid & (p - 1);
        int jj = ((tid - k) << 1) + k;
        float c0r = sr[tid],      c0i = si[tid];
        float c1r = sr[tid + NQ], c1i = si[tid + NQ];
        int   ti = k << (8 - s);
        float wr = twr[ti];
        float wi = inverse ? -twi[ti] : twi[ti];
        float tr = c1r * wr - c1i * wi;
        float t2 = c1r * wi + c1i * wr;
        dr[jj]     = c0r + tr;  di[jj]     = c0i + t2;
        dr[jj + p] = c0r - tr;  di[jj + p] = c0i - t2;
        float* tmp;
        tmp = sr; sr = dr; dr = tmp;
        tmp = si; si = di; di = tmp;
    }
    __syncthreads();
}

// X (LDS, Xr/Xi) -> irfft -> *win -> store frame to Ft (global, 1024 floats)
__device__ __forceinline__ void istft_frame(SMem& sm, float* Ft, int tid) {
    // Z[k] = E + iO = 0.5*(X[k]+conj(X[512-k])) + 0.5i * e^{+2pi ik/1024}*(X[k]-conj(X[512-k]))
    for (int k = tid; k < NH; k += NT) {
        float xr = sm.Xr[k], xi = sm.Xi[k];
        int   k2 = NH - k;                       // 512 at k==0
        float yr = sm.Xr[k2], yi = -sm.Xi[k2];
        float er = xr + yr, ei = xi + yi;        // 2E
        float dr = xr - yr, di = xi - yi;        // 2 W^k O
        float c  = sm.w1r[k], s = sm.w1i[k];     // e^{+2pi k/1024}
        float wdr = c * dr - s * di;             // 2O
        float wdi = c * di + s * dr;
        sm.Ar[k] = (er - wdi) * (1.0f / 1024.0f);
        sm.Ai[k] = (ei + wdr) * (1.0f / 1024.0f);
    }
    float *srp = sm.Ar, *sip = sm.Ai, *drp = sm.Br, *dip = sm.Bi;
    fft512(srp, sip, drp, dip, sm.twr, sm.twi, tid, true);
    for (int n = tid; n < NH; n += NT) {
        float2 v;
        v.x = sm.win[2 * n]     * srp[n];
        v.y = sm.win[2 * n + 1] * sip[n];
        ((float2*)Ft)[n] = v;
    }
}

extern "C" __global__ __launch_bounds__(NT)
void k_init(const float* __restrict__ mel,     // [80,512]
            const float* __restrict__ invmel,  // [513,80]
            float* __restrict__ ws) {
    __shared__ SMem sm;
    const int tid = threadIdx.x;
    const int t   = blockIdx.x;

    // tables (fp64-accurate, in LDS; block 0 also persists to ws)
    for (int n = tid; n < NFFT; n += NT) {
        double a = (2.0 * 3.14159265358979323846) * (double)n / 1024.0;
        sm.win[n] = (float)(0.5 - 0.5 * cos(a));
    }
    for (int j = tid; j < NQ; j += NT) {
        double a = (2.0 * 3.14159265358979323846) * (double)j / 512.0;
        sm.twr[j] = (float)cos(a);
        sm.twi[j] = (float)(-sin(a));
    }
    for (int k = tid; k < NBINS; k += NT) {
        double a = (2.0 * 3.14159265358979323846) * (double)k / 1024.0;
        sm.w1r[k] = (float)cos(a);
        sm.w1i[k] = (float)sin(a);
    }
    __syncthreads();
    if (t == 0) {
        for (int n = tid; n < NFFT; n += NT) ws[TBL_WIN + n] = sm.win[n];
        for (int j = tid; j < NQ; j += NT) {
            ws[TBL_TWR + j] = sm.twr[j];
            ws[TBL_TWI + j] = sm.twi[j];
        }
        for (int k = tid; k < NBINS; k += NT) {
            ws[TBL_W1R + k] = sm.w1r[k];
            ws[TBL_W1I + k] = sm.w1i[k];
        }
    }

    // iws (grid-strided)
    for (int p = t * NT + tid; p < SIGLEN; p += NFR * NT) {
        int tq = p >> 6, io = p & 63;
        float s = 0.f;
#pragma unroll
        for (int m = 0; m < 16; ++m) {
            int tp = tq - m;
            if (tp >= 0 && tp < NFR) {
                float w = sm.win[io + (m << 6)];
                s += w * w;
            }
        }
        ws[OFF_IWS + p] = (s > 1e-11f) ? (1.0f / s) : 1.0f;
    }

    // mag column t: p = 10^mel[:,t]; mag = invmel @ p
    if (tid < NMELS) sm.xb[tid] = exp10f(mel[tid * NFR + t]);
    __syncthreads();
    for (int k = tid; k < NBINS; k += NT) {
        const float* row = invmel + k * NMELS;
        float s = 0.f;
#pragma unroll 8
        for (int j = 0; j < NMELS; ++j) s += row[j] * sm.xb[j];
        ws[OFF_MAG + t * NBINS + k] = s;
        sm.Xr[k] = s;            // X0 = mag (real)
        sm.Xi[k] = 0.f;
    }
    __syncthreads();

    // first istft frames -> F0
    istft_frame(sm, ws + OFF_F0 + (size_t)t * NFFT, tid);
}

extern "C" __global__ __launch_bounds__(NT)
void k_iter(const float* __restrict__ tbl,
            const float* __restrict__ magg,
            const float* __restrict__ iws,
            const float* __restrict__ Fin,
            float* __restrict__ Fout) {
    __shared__ SMem sm;
    const int tid = threadIdx.x;
    const int t   = blockIdx.x;

    // load tables + this column's mag
    for (int i = tid; i < NFFT; i += NT) sm.win[i] = tbl[TBL_WIN + i];
    for (int i = tid; i < NQ; i += NT) {
        sm.twr[i] = tbl[TBL_TWR + i];
        sm.twi[i] = tbl[TBL_TWI + i];
    }
    for (int i = tid; i < NBINS; i += NT) {
        sm.w1r[i] = tbl[TBL_W1R + i];
        sm.w1i[i] = tbl[TBL_W1I + i];
        sm.mag[i] = magg[(size_t)t * NBINS + i];
    }

    // OLA gather: x[t*64 + i] for i in 0..1023, normalized by iws
    const float* iw = iws + t * HOP;
    for (int q = 0; q < 4; ++q) {
        int i  = q * NT + tid;
        int tq = t + (i >> 6), io = i & 63;
        float s = 0.f;
#pragma unroll
        for (int m = 0; m < 16; ++m) {
            int tp = tq - m;
            if (tp >= 0 && tp < NFR)
                s += Fin[(size_t)tp * NFFT + io + (m << 6)];
        }
        sm.xb[i] = s * iw[i];
    }
    __syncthreads();

    // window + pack, forward FFT
    for (int n = tid; n < NH; n += NT) {
        sm.Ar[n] = sm.win[2 * n]     * sm.xb[2 * n];
        sm.Ai[n] = sm.win[2 * n + 1] * sm.xb[2 * n + 1];
    }
    float *srp = sm.Ar, *sip = sm.Ai, *drp = sm.Br, *dip = sm.Bi;
    fft512(srp, sip, drp, dip, sm.twr, sm.twi, tid, false);

    // unpack rfft + phase projection onto mag
    for (int k = tid; k < NH; k += NT) {
        int   k2 = (NH - k) & (NH - 1);
        float zr = srp[k],  zi = sip[k];
        float yr = srp[k2], yi = -sip[k2];
        float er = 0.5f * (zr + yr), ei = 0.5f * (zi + yi);
        float dr = zr - yr,          di = zi - yi;
        float odr = 0.5f * di, odi = -0.5f * dr;     // O = (z - conj)/2i
        float c = sm.w1r[k], s = -sm.w1i[k];         // e^{-2pi k/1024}
        float wor = c * odr - s * odi;
        float woi = c * odi + s * odr;
        float estr = er + wor, esti = ei + woi;
        float a  = sqrtf(estr * estr + esti * esti);
        float sc = sm.mag[k] / fmaxf(1e-8f, a);
        sm.Xr[k] = estr * sc;
        sm.Xi[k] = esti * sc;
        if (k == 0) {                                // Nyquist (real)
            float e5  = er - wor;
            float sc5 = sm.mag[NH] / fmaxf(1e-8f, fabsf(e5));
            sm.Xr[NH] = e5 * sc5;
            sm.Xi[NH] = 0.f;
        }
    }
    __syncthreads();

    // istft of new X -> Fout
    istft_frame(sm, Fout + (size_t)t * NFFT, tid);
}

extern "C" __global__ __launch_bounds__(NT)
void k_final(const float* __restrict__ iws,
             const float* __restrict__ F,
             float* __restrict__ out) {
    int p = blockIdx.x * NT + threadIdx.x;
    if (p >= SIGLEN) return;
    int tq = p >> 6, io = p & 63;
    float s = 0.f;
#pragma unroll
    for (int m = 0; m < 16; ++m) {
        int tp = tq - m;
        if (tp >= 0 && tp < NFR)
            s += F[(size_t)tp * NFFT + io + (m << 6)];
    }
    out[p] = s * iws[p];
}

extern "C" void kernel_launch(void* const* d_in, const int* in_sizes, int n_in,
                              void* d_out, int out_size, void* d_ws, size_t ws_size,
                              hipStream_t stream) {
    const float* mel    = (const float*)d_in[0];   // [80,512]
    const float* invmel = (const float*)d_in[1];   // [513,80]
    float* out = (float*)d_out;                    // [33728]
    float* ws  = (float*)d_ws;

    float* tbl  = ws;
    float* magg = ws + OFF_MAG;
    float* iws  = ws + OFF_IWS;
    float* F0   = ws + OFF_F0;
    float* F1   = ws + OFF_F1;

    k_init<<<NFR, NT, 0, stream>>>(mel, invmel, ws);
    for (int it = 0; it < NITER; ++it) {
        const float* fin = (it & 1) ? F1 : F0;
        float*       fout = (it & 1) ? F0 : F1;
        k_iter<<<NFR, NT, 0, stream>>>(tbl, magg, iws, fin, fout);
    }
    k_final<<<(SIGLEN + NT - 1) / NT, NT, 0, stream>>>(iws, F0, out);
}

// Round 3
// 3542.562 us; speedup vs baseline: 2.0054x; 2.0054x over previous
//
#include <hip/hip_runtime.h>
#include <math.h>

#define NFFT   1024
#define NH     512
#define HOP    64
#define NMELS  80
#define NFR    512
#define NBINS  513
#define NITER  300
#define SIGLEN 33728
#define NT     256

// ---- workspace layout (float offsets) — identical to the passing round ----
#define TBL_WIN  0          // win[1024]
#define TBL_TWR  1024       // twr[256]  e^{-2pi i j/512}.re
#define TBL_TWI  1280       // twi[256]  e^{-2pi i j/512}.im
#define TBL_W1R  1536       // w1r[513]  cos(2pi k/1024)
#define TBL_W1I  2056       // w1i[513]  sin(2pi k/1024)
#define OFF_MAG  4096                     // mag[512*513], stride 513
#define OFF_IWS  266752                   // iws[33728]
#define OFF_F0   300480                   // F0[512*1024]
#define OFF_F1   824768                   // F1[512*1024]

struct __align__(16) SMem {
    float xb[NFFT];               // packed windowed signal (float2 complex pairs)
    float C0r[NH], C0i[NH];       // FFT buffer A
    float C1r[NH], C1i[NH];       // FFT buffer B
    float win[NFFT];              // used by k_init only
    float twr[256], twi[256];     // e^{-2pi i j/512}
    float mag[516];               // used by k_init only
};

// ---- mixed-radix Stockham N=512 = 4*4*4*4*2, natural order in/out ----
// generic radix-4 stage: src[b+128q] -> dst[4(b-k)+k+q*p], twiddle W_{4p}^{qk}
template<int P, int SH, bool INV>
__device__ __forceinline__ void r4stage(const float* __restrict__ sR, const float* __restrict__ sI,
                                        float* __restrict__ dR, float* __restrict__ dI,
                                        const float* twr, const float* twi, int tid) {
    __syncthreads();
    if (tid < 128) {
        int k  = tid & (P - 1);
        int d0 = ((tid - k) << 2) + k;
        float x0r = sR[tid],       x0i = sI[tid];
        float x1r = sR[tid + 128], x1i = sI[tid + 128];
        float x2r = sR[tid + 256], x2i = sI[tid + 256];
        float x3r = sR[tid + 384], x3i = sI[tid + 384];
        int tb = k << SH;                      // k * (128/P)
        float c1 = twr[tb], s1 = twi[tb];
        if (INV) s1 = -s1;
        float c2 = c1 * c1 - s1 * s1, s2 = 2.f * c1 * s1;
        float c3 = c1 * c2 - s1 * s2, s3 = c1 * s2 + s1 * c2;
        float a1r = x1r * c1 - x1i * s1, a1i = x1r * s1 + x1i * c1;
        float a2r = x2r * c2 - x2i * s2, a2i = x2r * s2 + x2i * c2;
        float a3r = x3r * c3 - x3i * s3, a3i = x3r * s3 + x3i * c3;
        float t0r = x0r + a2r, t0i = x0i + a2i;
        float t1r = x0r - a2r, t1i = x0i - a2i;
        float t2r = a1r + a3r, t2i = a1i + a3i;
        float t3r = a1r - a3r, t3i = a1i - a3i;
        float i3r = INV ? -t3i : t3i;          // ∓ i*t3
        float i3i = INV ?  t3r : -t3r;
        dR[d0]         = t0r + t2r;  dI[d0]         = t0i + t2i;
        dR[d0 + P]     = t1r + i3r;  dI[d0 + P]     = t1i + i3i;
        dR[d0 + 2 * P] = t0r - t2r;  dI[d0 + 2 * P] = t0i - t2i;
        dR[d0 + 3 * P] = t1r - i3r;  dI[d0 + 3 * P] = t1i - i3i;
    }
}

// final radix-2 stage, p=256: src[tid], src[tid+256], twiddle W_512^tid
template<bool INV>
__device__ __forceinline__ void r2final(const float* __restrict__ sR, const float* __restrict__ sI,
                                        float* __restrict__ dR, float* __restrict__ dI,
                                        const float* twr, const float* twi, int tid) {
    __syncthreads();
    float c = twr[tid], s = twi[tid];
    if (INV) s = -s;
    float x0r = sR[tid], x0i = sI[tid];
    float x1r = sR[tid + 256], x1i = sI[tid + 256];
    float ar = x1r * c - x1i * s, ai = x1r * s + x1i * c;
    dR[tid]       = x0r + ar;  dI[tid]       = x0i + ai;
    dR[tid + 256] = x0r - ar;  dI[tid + 256] = x0i - ai;
    __syncthreads();
}

// forward stage 0 (p=1, no twiddle): reads packed z from xb, writes C0[4b+q] as float4
__device__ __forceinline__ void fwd_stage0(SMem& sm, int tid) {
    __syncthreads();
    if (tid < 128) {
        const float2* z = (const float2*)sm.xb;
        float2 x0 = z[tid], x1 = z[tid + 128], x2 = z[tid + 256], x3 = z[tid + 384];
        float t0r = x0.x + x2.x, t0i = x0.y + x2.y;
        float t1r = x0.x - x2.x, t1i = x0.y - x2.y;
        float t2r = x1.x + x3.x, t2i = x1.y + x3.y;
        float t3r = x1.x - x3.x, t3i = x1.y - x3.y;
        float4 vr = make_float4(t0r + t2r, t1r + t3i, t0r - t2r, t1r - t3i);
        float4 vi = make_float4(t0i + t2i, t1i - t3r, t0i - t2i, t1i + t3r);
        ((float4*)sm.C0r)[tid] = vr;
        ((float4*)sm.C0i)[tid] = vi;
    }
}

// inverse stage 0 (p=1, no twiddle): reads A from C1, writes C0[4b+q] as float4
__device__ __forceinline__ void inv_stage0(SMem& sm, int tid) {
    __syncthreads();
    if (tid < 128) {
        float x0r = sm.C1r[tid],       x0i = sm.C1i[tid];
        float x1r = sm.C1r[tid + 128], x1i = sm.C1i[tid + 128];
        float x2r = sm.C1r[tid + 256], x2i = sm.C1i[tid + 256];
        float x3r = sm.C1r[tid + 384], x3i = sm.C1i[tid + 384];
        float t0r = x0r + x2r, t0i = x0i + x2i;
        float t1r = x0r - x2r, t1i = x0i - x2i;
        float t2r = x1r + x3r, t2i = x1i + x3i;
        float t3r = x1r - x3r, t3i = x1i - x3i;
        float4 vr = make_float4(t0r + t2r, t1r - t3i, t0r - t2r, t1r + t3i);
        float4 vi = make_float4(t0i + t2i, t1i + t3r, t0i - t2i, t1i - t3r);
        ((float4*)sm.C0r)[tid] = vr;
        ((float4*)sm.C0i)[tid] = vi;
    }
}

__device__ __forceinline__ void fft_fwd(SMem& sm, int tid) {
    fwd_stage0(sm, tid);                                                 // xb -> C0
    r4stage<4, 5, false>(sm.C0r, sm.C0i, sm.C1r, sm.C1i, sm.twr, sm.twi, tid);
    r4stage<16, 3, false>(sm.C1r, sm.C1i, sm.C0r, sm.C0i, sm.twr, sm.twi, tid);
    r4stage<64, 1, false>(sm.C0r, sm.C0i, sm.C1r, sm.C1i, sm.twr, sm.twi, tid);
    r2final<false>(sm.C1r, sm.C1i, sm.C0r, sm.C0i, sm.twr, sm.twi, tid); // -> C0
}

__device__ __forceinline__ void fft_inv(SMem& sm, int tid) {
    inv_stage0(sm, tid);                                                 // C1 -> C0
    r4stage<4, 5, true>(sm.C0r, sm.C0i, sm.C1r, sm.C1i, sm.twr, sm.twi, tid);
    r4stage<16, 3, true>(sm.C1r, sm.C1i, sm.C0r, sm.C0i, sm.twr, sm.twi, tid);
    r4stage<64, 1, true>(sm.C0r, sm.C0i, sm.C1r, sm.C1i, sm.twr, sm.twi, tid);
    r2final<true>(sm.C1r, sm.C1i, sm.C0r, sm.C0i, sm.twr, sm.twi, tid);  // -> C0
}

extern "C" __global__ __launch_bounds__(NT)
void k_init(const float* __restrict__ mel,     // [80,512]
            const float* __restrict__ invmel,  // [513,80]
            float* __restrict__ ws) {
    __shared__ SMem sm;
    const int tid = threadIdx.x;
    const int t   = blockIdx.x;

    for (int n = tid; n < NFFT; n += NT) {
        double a = (2.0 * 3.14159265358979323846) * (double)n / 1024.0;
        sm.win[n] = (float)(0.5 - 0.5 * cos(a));
    }
    for (int j = tid; j < 256; j += NT) {
        double a = (2.0 * 3.14159265358979323846) * (double)j / 512.0;
        sm.twr[j] = (float)cos(a);
        sm.twi[j] = (float)(-sin(a));
    }
    __syncthreads();
    if (t == 0) {
        for (int n = tid; n < NFFT; n += NT) ws[TBL_WIN + n] = sm.win[n];
        for (int j = tid; j < 256; j += NT) {
            ws[TBL_TWR + j] = sm.twr[j];
            ws[TBL_TWI + j] = sm.twi[j];
        }
        for (int k = tid; k < NBINS; k += NT) {
            double a = (2.0 * 3.14159265358979323846) * (double)k / 1024.0;
            ws[TBL_W1R + k] = (float)cos(a);
            ws[TBL_W1I + k] = (float)sin(a);
        }
    }

    // inv window-sum-squares (grid-strided)
    for (int p = t * NT + tid; p < SIGLEN; p += NFR * NT) {
        int tq = p >> 6, io = p & 63;
        float s = 0.f;
#pragma unroll
        for (int m = 0; m < 16; ++m) {
            int tp = tq - m;
            if (tp >= 0 && tp < NFR) {
                float w = sm.win[io + (m << 6)];
                s += w * w;
            }
        }
        ws[OFF_IWS + p] = (s > 1e-11f) ? (1.0f / s) : 1.0f;
    }

    // mag column t
    if (tid < NMELS) sm.xb[tid] = exp10f(mel[tid * NFR + t]);
    __syncthreads();
    for (int k = tid; k < NBINS; k += NT) {
        const float* row = invmel + k * NMELS;
        float s = 0.f;
#pragma unroll 8
        for (int j = 0; j < NMELS; ++j) s += row[j] * sm.xb[j];
        ws[OFF_MAG + t * NBINS + k] = s;
        sm.mag[k] = s;
    }
    __syncthreads();

    // A[k] from real X = mag:  A = ((x+y) - s*dr, c*dr)/1024, y = mag[512-k]
    for (int k = tid; k < NH; k += NT) {
        float xr = sm.mag[k], yr = sm.mag[512 - k];
        double a = (2.0 * 3.14159265358979323846) * (double)k / 1024.0;
        float c = (float)cos(a), s = (float)sin(a);
        float dr = xr - yr;
        sm.C1r[k] = ((xr + yr) - s * dr) * (1.0f / 1024.0f);
        sm.C1i[k] = (c * dr) * (1.0f / 1024.0f);
    }
    fft_inv(sm, tid);

    // windowed frame store
    float4 w4 = ((float4*)sm.win)[tid];
    float4 o;
    o.x = w4.x * sm.C0r[2 * tid];
    o.y = w4.y * sm.C0i[2 * tid];
    o.z = w4.z * sm.C0r[2 * tid + 1];
    o.w = w4.w * sm.C0i[2 * tid + 1];
    *(float4*)&ws[OFF_F0 + (t << 10) + (tid << 2)] = o;
}

extern "C" __global__ __launch_bounds__(NT)
void k_iter(const float* __restrict__ tbl,
            const float* __restrict__ magg,
            const float* __restrict__ iws,
            const float* __restrict__ Fin,
            float* __restrict__ Fout) {
    __shared__ SMem sm;
    const int tid  = threadIdx.x;
    const int t    = blockIdx.x;
    const int t513 = t * NBINS;

    // ---- hoisted global scalar loads for the projection step ----
    const int j2 = 512 - tid;
    float m_a, m_b, m_ny = 0.f, w1r_a, w1i_a, w1r_b, w1i_b;
    if (tid == 0) {
        m_a  = magg[t513];
        m_ny = magg[t513 + 512];
        m_b  = magg[t513 + 256];
        w1r_a = 1.f; w1i_a = 0.f; w1r_b = 0.f; w1i_b = 1.f;
    } else {
        m_a   = magg[t513 + tid];
        m_b   = magg[t513 + j2];
        w1r_a = tbl[TBL_W1R + tid]; w1i_a = tbl[TBL_W1I + tid];
        w1r_b = tbl[TBL_W1R + j2];  w1i_b = tbl[TBL_W1I + j2];
    }

    // ---- stage tables: window float4 (kept in register), twiddles to LDS ----
    float4 w4 = ((const float4*)(tbl + TBL_WIN))[tid];
    if (tid < 64)        ((float4*)sm.twr)[tid]      = ((const float4*)(tbl + TBL_TWR))[tid];
    else if (tid < 128)  ((float4*)sm.twi)[tid - 64] = ((const float4*)(tbl + TBL_TWI))[tid - 64];

    // ---- OLA gather (float4), * iws * win -> xb ----
    const int i0 = tid << 2;
    const int io = i0 & 63;
    const int tq = t + (i0 >> 6);
    float4 acc = make_float4(0.f, 0.f, 0.f, 0.f);
#pragma unroll
    for (int m = 0; m < 16; ++m) {
        int tp = tq - m;
        if (tp >= 0 && tp < NFR) {
            float4 v = *(const float4*)&Fin[(tp << 10) + io + (m << 6)];
            acc.x += v.x; acc.y += v.y; acc.z += v.z; acc.w += v.w;
        }
    }
    float4 iw = *(const float4*)&iws[(t << 6) + i0];
    float4 xv;
    xv.x = acc.x * iw.x * w4.x;
    xv.y = acc.y * iw.y * w4.y;
    xv.z = acc.z * iw.z * w4.z;
    xv.w = acc.w * iw.w * w4.w;
    ((float4*)sm.xb)[tid] = xv;

    // ---- forward FFT (xb packed z -> C0 = Z) ----
    fft_fwd(sm, tid);

    // ---- fused unpack + phase projection + iFFT prep: Z (C0) -> A (C1) ----
    if (tid == 0) {
        float zr = sm.C0r[0], zi = sm.C0i[0];
        float e0 = zr + zi;                 // est[0]   (real)
        float e5 = zr - zi;                 // est[512] (real)
        float X0 = m_a  * e0 / fmaxf(1e-8f, fabsf(e0));
        float X5 = m_ny * e5 / fmaxf(1e-8f, fabsf(e5));
        sm.C1r[0] = (X0 + X5) * (1.0f / 1024.0f);
        sm.C1i[0] = (X0 - X5) * (1.0f / 1024.0f);
        float z6r = sm.C0r[256], z6i = sm.C0i[256];
        float sc6 = m_b / fmaxf(1e-8f, sqrtf(z6r * z6r + z6i * z6i));
        float X6r = z6r * sc6, X6i = -z6i * sc6;   // est[256] = (z6r, -z6i)
        sm.C1r[256] = X6r * (2.0f / 1024.0f);
        sm.C1i[256] = -X6i * (2.0f / 1024.0f);
    } else {
        float zr = sm.C0r[tid], zi = sm.C0i[tid];
        float ur = sm.C0r[j2],  ui = sm.C0i[j2];
        float er = 0.5f * (zr + ur), ei = 0.5f * (zi - ui);
        float dr = zr - ur,          di = zi + ui;
        float odr = 0.5f * di, odi = -0.5f * dr;
        float e1r = er + w1r_a * odr + w1i_a * odi;
        float e1i = ei + w1r_a * odi - w1i_a * odr;
        float e2r =  er + w1r_b * odr - w1i_b * odi;
        float e2i = -ei - w1r_b * odi - w1i_b * odr;
        float sc1 = m_a / fmaxf(1e-8f, sqrtf(e1r * e1r + e1i * e1i));
        float sc2 = m_b / fmaxf(1e-8f, sqrtf(e2r * e2r + e2i * e2i));
        float X1r = e1r * sc1, X1i = e1i * sc1;
        float X2r = e2r * sc2, X2i = e2i * sc2;
        float Er = X1r + X2r, Ei = X1i - X2i;
        float Dr = X1r - X2r, Di = X1i + X2i;
        float wdr = w1r_a * Dr - w1i_a * Di, wdi = w1r_a * Di + w1i_a * Dr;
        sm.C1r[tid] = (Er - wdi) * (1.0f / 1024.0f);
        sm.C1i[tid] = (Ei + wdr) * (1.0f / 1024.0f);
        float wdr2 = -w1r_b * Dr - w1i_b * Di, wdi2 = w1r_b * Di - w1i_b * Dr;
        sm.C1r[j2] = (Er - wdi2) * (1.0f / 1024.0f);
        sm.C1i[j2] = (-Ei + wdr2) * (1.0f / 1024.0f);
    }

    // ---- inverse FFT (A in C1 -> C0) ----
    fft_inv(sm, tid);

    // ---- windowed frame store ----
    float4 o;
    o.x = w4.x * sm.C0r[2 * tid];
    o.y = w4.y * sm.C0i[2 * tid];
    o.z = w4.z * sm.C0r[2 * tid + 1];
    o.w = w4.w * sm.C0i[2 * tid + 1];
    *(float4*)&Fout[(t << 10) + i0] = o;
}

extern "C" __global__ __launch_bounds__(NT)
void k_final(const float* __restrict__ iws,
             const float* __restrict__ F,
             float* __restrict__ out) {
    int p0 = (blockIdx.x * NT + threadIdx.x) << 2;
    if (p0 >= SIGLEN) return;
    int tq = p0 >> 6, io = p0 & 63;
    float4 acc = make_float4(0.f, 0.f, 0.f, 0.f);
#pragma unroll
    for (int m = 0; m < 16; ++m) {
        int tp = tq - m;
        if (tp >= 0 && tp < NFR) {
            float4 v = *(const float4*)&F[(tp << 10) + io + (m << 6)];
            acc.x += v.x; acc.y += v.y; acc.z += v.z; acc.w += v.w;
        }
    }
    float4 iw = *(const float4*)&iws[p0];
    float4 o = make_float4(acc.x * iw.x, acc.y * iw.y, acc.z * iw.z, acc.w * iw.w);
    *(float4*)&out[p0] = o;
}

extern "C" void kernel_launch(void* const* d_in, const int* in_sizes, int n_in,
                              void* d_out, int out_size, void* d_ws, size_t ws_size,
                              hipStream_t stream) {
    const float* mel    = (const float*)d_in[0];
    const float* invmel = (const float*)d_in[1];
    float* out = (float*)d_out;
    float* ws  = (float*)d_ws;

    float* tbl  = ws;
    float* magg = ws + OFF_MAG;
    float* iws  = ws + OFF_IWS;
    float* F0   = ws + OFF_F0;
    float* F1   = ws + OFF_F1;

    k_init<<<NFR, NT, 0, stream>>>(mel, invmel, ws);
    for (int it = 0; it < NITER; ++it) {
        const float* fin  = (it & 1) ? F1 : F0;
        float*       fout = (it & 1) ? F0 : F1;
        k_iter<<<NFR, NT, 0, stream>>>(tbl, magg, iws, fin, fout);
    }
    k_final<<<(SIGLEN / 4 + NT - 1) / NT, NT, 0, stream>>>(iws, F0, out);
}